// Round 2
// baseline (313.448 us; speedup 1.0000x reference)
//
#include <hip/hip_runtime.h>
#include <hip/hip_bf16.h>

#define NN 100000   // nodes
#define FF 10       // input features
#define HH 20       // hidden dim
#define GG 512      // graphs
#define LL 2        // labels

#define NB 500      // dst buckets
#define BNODES 200  // nodes per bucket (NN / NB)
#define CAP 7168    // per-bucket capacity (mean 6400, ~9.6 sigma)
#define HB 100      // nodes per half-bucket (one layer block)
#define SCAP 3712   // per-half-bucket edge capacity (mean 3200, ~9 sigma)
#define TILE 4096   // edges per block in multisplit
#define SRC_BITS 17
#define SRC_MASK 0x1FFFFu
#define XPAD 16     // x stored padded to 16 bf16 (32B): 2 x uint4 lanes
#define HPAD 24     // h stored padded to 24 bf16 (48B): 3 x uint4 lanes

// bf16 helpers (storage-only; all math in f32)
__device__ inline unsigned short f2bf(float f) {
  unsigned u = __float_as_uint(f);
  unsigned r = u + 0x7FFFu + ((u >> 16) & 1u);
  return (unsigned short)(r >> 16);
}
__device__ inline float bflo(unsigned u) { return __uint_as_float(u << 16); }
__device__ inline float bfhi(unsigned u) { return __uint_as_float(u & 0xFFFF0000u); }

// ---------------------------------------------------------------------------
// Cast x f32->bf16 into PADDED rows (16 elems, pad=0) and zero cursors/pools.
// ---------------------------------------------------------------------------
__global__ __launch_bounds__(256) void cast_init_kernel(
    const float* __restrict__ x, unsigned short* __restrict__ xb,
    float* __restrict__ sump, int* __restrict__ maxp, float* __restrict__ cnt,
    int* __restrict__ cursor, int n16) {
  int i = blockIdx.x * 256 + threadIdx.x;
  if (i < n16) {
    int node = i >> 4;
    int f = i & 15;
    float v = 0.0f;
    if (f < FF) v = __builtin_nontemporal_load(x + (size_t)node * FF + f);
    xb[i] = f2bf(v);
  }
  if (i < GG * HH) {
    sump[i] = 0.0f;
    maxp[i] = 0;
  }
  if (i < GG) cnt[i] = 0.0f;
  if (i < NB) cursor[i] = 0;
}

// ---------------------------------------------------------------------------
// Multisplit (512 thr) with LDS-staged COALESCED writes into fixed-CAP bucket
// regions. Payload pack: (local_dst << 17) | src.   (unchanged)
// ---------------------------------------------------------------------------
__global__ __launch_bounds__(512) void multisplit_kernel(
    const int* __restrict__ src, const int* __restrict__ dst,
    int* __restrict__ cursor, unsigned int* __restrict__ pay, int E) {
  __shared__ int lhist[NB];
  __shared__ int lofs[NB];
  __shared__ int gbase[NB];
  __shared__ int lcur[NB];
  __shared__ unsigned int sord[TILE];
  __shared__ unsigned short sdbk[TILE];
  __shared__ int ss[512];
  int t = threadIdx.x;
  if (t < NB) lhist[t] = 0;
  __syncthreads();

  int base = blockIdx.x * TILE;
  int count = E - base;
  if (count > TILE) count = TILE;

  for (int i = t; i < count; i += 512)
    atomicAdd(&lhist[dst[base + i] / BNODES], 1);
  __syncthreads();

  int own = (t < NB) ? lhist[t] : 0;
  ss[t] = own;
  __syncthreads();
  for (int off = 1; off < 512; off <<= 1) {
    int a0 = (t >= off) ? ss[t - off] : 0;
    __syncthreads();
    ss[t] += a0;
    __syncthreads();
  }
  if (t < NB) {
    lofs[t] = ss[t] - own;
    int bo = own ? atomicAdd(&cursor[t], own) : 0;
    if (bo > CAP - own) bo = CAP - own;
    gbase[t] = t * CAP + bo;
    lcur[t] = 0;
  }
  __syncthreads();

  for (int i = t; i < count; i += 512) {
    int e = base + i;
    int d = __builtin_nontemporal_load(dst + e);
    int s = __builtin_nontemporal_load(src + e);
    int bk = d / BNODES;
    int ld = d - bk * BNODES;
    int r = atomicAdd(&lcur[bk], 1);
    int slot = lofs[bk] + r;
    sord[slot] = ((unsigned)ld << SRC_BITS) | (unsigned)s;
    sdbk[slot] = (unsigned short)bk;
  }
  __syncthreads();

  for (int i = t; i < count; i += 512) {
    int bk = sdbk[i];
    pay[gbase[bk] + (i - lofs[bk])] = sord[i];
  }
}

// ---------------------------------------------------------------------------
// One-time CSR finalize (unchanged): segment per node is contiguous, and
// rend[ln] == rofs[ln+1] within a bucket (dense segments).
// ---------------------------------------------------------------------------
__global__ __launch_bounds__(256) void bucket_csr_kernel(
    const unsigned int* __restrict__ pay, const int* __restrict__ cursor,
    int* __restrict__ srt, int* __restrict__ rofs, int* __restrict__ rend) {
  __shared__ int lhist[BNODES];
  __shared__ int lofs[BNODES];
  __shared__ int lcur[BNODES];
  __shared__ int ss[256];
  int b = blockIdx.x;
  int t = threadIdx.x;
  int k0 = b * CAP;
  int ecnt = cursor[b];
  if (ecnt > CAP) ecnt = CAP;

  if (t < BNODES) lhist[t] = 0;
  __syncthreads();
  for (int k = t; k < ecnt; k += 256)
    atomicAdd(&lhist[pay[k0 + k] >> SRC_BITS], 1);
  __syncthreads();

  int own = (t < BNODES) ? lhist[t] : 0;
  ss[t] = own;
  __syncthreads();
  for (int off = 1; off < 256; off <<= 1) {
    int a0 = (t >= off) ? ss[t - off] : 0;
    __syncthreads();
    ss[t] += a0;
    __syncthreads();
  }
  if (t < BNODES) {
    int ex = ss[t] - own;
    lofs[t] = ex;
    lcur[t] = 0;
    rofs[b * BNODES + t] = k0 + ex;
    rend[b * BNODES + t] = k0 + ex + own;
  }
  __syncthreads();

  for (int k = t; k < ecnt; k += 256) {
    unsigned p = pay[k0 + k];
    int ld = p >> SRC_BITS;
    int r = atomicAdd(&lcur[ld], 1);
    srt[k0 + lofs[ld] + r] = (int)(p & SRC_MASK);
  }
}

// ---------------------------------------------------------------------------
// Fused HALF-bucket layer, v3 (= v2 + separate OUTPUT stride DSO):
//  - gather: BALANCED edge ranges. 512 threads = NG groups of CL lanes; each
//    group takes a contiguous slice of the sorted segment; uniform uint4
//    (16B) loads per lane (padded rows); register accumulate; atomicAdd
//    flush into LDS acc at node boundaries (binary search on sRofs,
//    segments are dense).
//  - dense: 4 outputs per thread (HB*5 threads), output dims always HH=20,
//    written with stride DSO; tail [HH, DSO) zeroed.
// ---------------------------------------------------------------------------
template<int DL, int DSI, int DSO>
__global__ __launch_bounds__(512) void layer_kernel(
    const unsigned short* __restrict__ hin, const int* __restrict__ srt,
    const int* __restrict__ rofs, const int* __restrict__ rend,
    const float* __restrict__ Wrel, const float* __restrict__ bias,
    const float* __restrict__ Wroot, unsigned short* __restrict__ hout) {
  constexpr int CL = DSI / 8;       // lanes per group (2 for x, 3 for h)
  constexpr int NG = 512 / CL;      // groups per block
  constexpr int AST = DSI + 1;      // acc stride (odd -> bank spread)
  __shared__ int sSrc[SCAP];
  __shared__ float acc[HB * AST];
  __shared__ float rootsf[HB * DL];
  __shared__ __align__(16) float sWrel[DL * HH];
  __shared__ __align__(16) float sWroot[DL * HH];
  __shared__ float sb[HH];
  __shared__ int sRofs[HB];
  __shared__ int sRend[HB];
  __shared__ int sSeg0, sSegLen;
  int b2 = blockIdx.x;
  int t = threadIdx.x;
  int nbase = b2 * HB;

  for (int i = t; i < DL * HH; i += 512) {
    sWrel[i] = Wrel[i];
    sWroot[i] = Wroot[i];
  }
  if (t < HH) sb[t] = bias[t];
  if (t < HB) {
    sRofs[t] = rofs[nbase + t];
    sRend[t] = rend[nbase + t];
  }
  if (t == 0) {
    int s0 = rofs[nbase];
    int sl = rend[nbase + HB - 1] - s0;
    sSeg0 = s0;
    sSegLen = sl < SCAP ? sl : SCAP;
  }
  // roots -> f32 LDS (compact DL elems out of padded DSI rows)
  for (int i = t; i < HB * (DL / 2); i += 512) {
    int ln = i / (DL / 2);
    int p = i - ln * (DL / 2);
    unsigned u = *(const unsigned*)(hin + (size_t)(nbase + ln) * DSI + 2 * p);
    rootsf[ln * DL + 2 * p] = bflo(u);
    rootsf[ln * DL + 2 * p + 1] = bfhi(u);
  }
  for (int i = t; i < HB * AST; i += 512) acc[i] = 0.0f;
  __syncthreads();

  int seg0 = sSeg0, seglen = sSegLen;
  for (int i = t; i < seglen; i += 512)
    sSrc[i] = __builtin_nontemporal_load(srt + seg0 + i);
  __syncthreads();

  // ---- balanced gather ----
  int g = t / CL;
  int c = t - g * CL;
  if (g < NG) {
    int W = (seglen + NG - 1) / NG;
    int a = g * W;
    if (a > seglen) a = seglen;
    int b = a + W;
    if (b > seglen) b = seglen;
    if (a < b) {
      // binary search: largest ln with sRofs[ln]-seg0 <= a
      int lo = 0, hi = HB - 1;
      while (lo < hi) {
        int mid = (lo + hi + 1) >> 1;
        if (sRofs[mid] - seg0 <= a) lo = mid; else hi = mid - 1;
      }
      int ln = lo;
      const unsigned short* basep = hin + c * 8;
      float a0 = 0, a1 = 0, a2 = 0, a3 = 0, a4 = 0, a5 = 0, a6 = 0, a7 = 0;
      int k = a;
      while (k < b) {
        int lim = sRend[ln] - seg0;
        if (lim > b) lim = b;
#pragma clang loop unroll_count(4)
        for (; k < lim; ++k) {
          int s = sSrc[k];
          uint4 u = *(const uint4*)(basep + (size_t)s * DSI);
          a0 += bflo(u.x); a1 += bfhi(u.x);
          a2 += bflo(u.y); a3 += bfhi(u.y);
          a4 += bflo(u.z); a5 += bfhi(u.z);
          a6 += bflo(u.w); a7 += bfhi(u.w);
        }
        float* ap = acc + ln * AST + c * 8;
        atomicAdd(ap + 0, a0); atomicAdd(ap + 1, a1);
        atomicAdd(ap + 2, a2); atomicAdd(ap + 3, a3);
        atomicAdd(ap + 4, a4); atomicAdd(ap + 5, a5);
        atomicAdd(ap + 6, a6); atomicAdd(ap + 7, a7);
        a0 = a1 = a2 = a3 = a4 = a5 = a6 = a7 = 0.0f;
        ln++;
      }
    }
  }
  __syncthreads();

  // ---- dense: 4 outputs / thread, output stride DSO ----
  if (t < HB * 5) {
    int ln = t / 5;
    int jg = t - ln * 5;
    int j0 = jg * 4;
    float v0 = sb[j0], v1 = sb[j0 + 1], v2 = sb[j0 + 2], v3 = sb[j0 + 3];
    const float* ap = acc + ln * AST;
    const float* rp = rootsf + ln * DL;
#pragma unroll
    for (int f = 0; f < DL; ++f) {
      float af = ap[f], rf = rp[f];
      float4 wr = *(const float4*)(sWrel + f * HH + j0);
      float4 wo = *(const float4*)(sWroot + f * HH + j0);
      v0 += af * wr.x + rf * wo.x;
      v1 += af * wr.y + rf * wo.y;
      v2 += af * wr.z + rf * wo.z;
      v3 += af * wr.w + rf * wo.w;
    }
    unsigned short* orow = hout + (size_t)(nbase + ln) * DSO;
    uint2 o;
    o.x = ((unsigned)f2bf(fmaxf(v1, 0.0f)) << 16) | f2bf(fmaxf(v0, 0.0f));
    o.y = ((unsigned)f2bf(fmaxf(v3, 0.0f)) << 16) | f2bf(fmaxf(v2, 0.0f));
    *(uint2*)(orow + j0) = o;
  }
  // zero the padded tail so the next layer's gather adds zeros
  if (t < HB) {
    unsigned short* orow = hout + (size_t)(nbase + t) * DSO;
#pragma unroll
    for (int e = HH; e < DSO; ++e) orow[e] = 0;
  }
}

// ---------------------------------------------------------------------------
// Layer 3 + pooling: same balanced gather + register dense, then block-local
// pool scan + few global atomics (post-ReLU >=0 -> int atomicMax is ordered).
// ---------------------------------------------------------------------------
__global__ __launch_bounds__(512) void layer_pool_kernel(
    const unsigned short* __restrict__ hin, const int* __restrict__ srt,
    const int* __restrict__ rofs, const int* __restrict__ rend,
    const float* __restrict__ Wrel, const float* __restrict__ bias,
    const float* __restrict__ Wroot, const int* __restrict__ batch,
    float* __restrict__ sump, int* __restrict__ maxp,
    float* __restrict__ cnt) {
  constexpr int DL = 20, DSI = 24, CL = 3, NG = 170, AST = 25;
  __shared__ int sSrc[SCAP];
  __shared__ float acc[HB * AST];
  __shared__ float rootsf[HB * DL];
  __shared__ __align__(16) float sWrel[DL * HH];
  __shared__ __align__(16) float sWroot[DL * HH];
  __shared__ float sb[HH];
  __shared__ int sRofs[HB];
  __shared__ int sRend[HB];
  __shared__ int sBatch[HB];
  __shared__ int sSeg0, sSegLen;
  int b2 = blockIdx.x;
  int t = threadIdx.x;
  int nbase = b2 * HB;

  for (int i = t; i < DL * HH; i += 512) {
    sWrel[i] = Wrel[i];
    sWroot[i] = Wroot[i];
  }
  if (t < HH) sb[t] = bias[t];
  if (t < HB) {
    sRofs[t] = rofs[nbase + t];
    sRend[t] = rend[nbase + t];
    sBatch[t] = batch[nbase + t];
  }
  if (t == 0) {
    int s0 = rofs[nbase];
    int sl = rend[nbase + HB - 1] - s0;
    sSeg0 = s0;
    sSegLen = sl < SCAP ? sl : SCAP;
  }
  for (int i = t; i < HB * (DL / 2); i += 512) {
    int ln = i / (DL / 2);
    int p = i - ln * (DL / 2);
    unsigned u = *(const unsigned*)(hin + (size_t)(nbase + ln) * DSI + 2 * p);
    rootsf[ln * DL + 2 * p] = bflo(u);
    rootsf[ln * DL + 2 * p + 1] = bfhi(u);
  }
  for (int i = t; i < HB * AST; i += 512) acc[i] = 0.0f;
  __syncthreads();

  int seg0 = sSeg0, seglen = sSegLen;
  for (int i = t; i < seglen; i += 512)
    sSrc[i] = __builtin_nontemporal_load(srt + seg0 + i);
  __syncthreads();

  // ---- balanced gather ----
  int g = t / CL;
  int c = t - g * CL;
  if (g < NG) {
    int W = (seglen + NG - 1) / NG;
    int a = g * W;
    if (a > seglen) a = seglen;
    int b = a + W;
    if (b > seglen) b = seglen;
    if (a < b) {
      int lo = 0, hi = HB - 1;
      while (lo < hi) {
        int mid = (lo + hi + 1) >> 1;
        if (sRofs[mid] - seg0 <= a) lo = mid; else hi = mid - 1;
      }
      int ln = lo;
      const unsigned short* basep = hin + c * 8;
      float a0 = 0, a1 = 0, a2 = 0, a3 = 0, a4 = 0, a5 = 0, a6 = 0, a7 = 0;
      int k = a;
      while (k < b) {
        int lim = sRend[ln] - seg0;
        if (lim > b) lim = b;
#pragma clang loop unroll_count(4)
        for (; k < lim; ++k) {
          int s = sSrc[k];
          uint4 u = *(const uint4*)(basep + (size_t)s * DSI);
          a0 += bflo(u.x); a1 += bfhi(u.x);
          a2 += bflo(u.y); a3 += bfhi(u.y);
          a4 += bflo(u.z); a5 += bfhi(u.z);
          a6 += bflo(u.w); a7 += bfhi(u.w);
        }
        float* ap = acc + ln * AST + c * 8;
        atomicAdd(ap + 0, a0); atomicAdd(ap + 1, a1);
        atomicAdd(ap + 2, a2); atomicAdd(ap + 3, a3);
        atomicAdd(ap + 4, a4); atomicAdd(ap + 5, a5);
        atomicAdd(ap + 6, a6); atomicAdd(ap + 7, a7);
        a0 = a1 = a2 = a3 = a4 = a5 = a6 = a7 = 0.0f;
        ln++;
      }
    }
  }
  __syncthreads();

  // ---- dense into registers (acc still needed as input) ----
  float v0 = 0, v1 = 0, v2 = 0, v3 = 0;
  int ln0 = 0, j0 = 0;
  if (t < HB * 5) {
    ln0 = t / 5;
    int jg = t - ln0 * 5;
    j0 = jg * 4;
    v0 = sb[j0]; v1 = sb[j0 + 1]; v2 = sb[j0 + 2]; v3 = sb[j0 + 3];
    const float* ap = acc + ln0 * AST;
    const float* rp = rootsf + ln0 * DL;
#pragma unroll
    for (int f = 0; f < DL; ++f) {
      float af = ap[f], rf = rp[f];
      float4 wr = *(const float4*)(sWrel + f * HH + j0);
      float4 wo = *(const float4*)(sWroot + f * HH + j0);
      v0 += af * wr.x + rf * wo.x;
      v1 += af * wr.y + rf * wo.y;
      v2 += af * wr.z + rf * wo.z;
      v3 += af * wr.w + rf * wo.w;
    }
    v0 = fmaxf(v0, 0.0f); v1 = fmaxf(v1, 0.0f);
    v2 = fmaxf(v2, 0.0f); v3 = fmaxf(v3, 0.0f);
  }
  __syncthreads();
  if (t < HB * 5) {
    float* ap = acc + ln0 * AST + j0;
    ap[0] = v0; ap[1] = v1; ap[2] = v2; ap[3] = v3;
  }
  __syncthreads();

  // ---- block-local pool + global atomics ----
  int g0 = sBatch[0];
  int g1 = sBatch[HB - 1];
  int ngr = g1 - g0 + 1;
  for (int it = t; it < ngr * HH; it += 512) {
    int gi = it / HH;
    int j = it - gi * HH;
    int gph = g0 + gi;
    float s = 0.0f, m = 0.0f;
    int c2 = 0;
    for (int ln = 0; ln < HB; ln++) {
      if (sBatch[ln] == gph) {
        float v = acc[ln * AST + j];
        s += v;
        m = fmaxf(m, v);
        c2++;
      }
    }
    if (c2) {
      atomicAdd(&sump[gph * HH + j], s);
      atomicMax(&maxp[gph * HH + j], __float_as_int(m));
      if (j == 0) atomicAdd(&cnt[gph], (float)c2);
    }
  }
}

__global__ __launch_bounds__(256) void readout_kernel(
    const float* __restrict__ sump, const int* __restrict__ maxp,
    const float* __restrict__ cnt, const float* __restrict__ Wlin,
    const float* __restrict__ blin, float* __restrict__ out) {
  int idx = blockIdx.x * 256 + threadIdx.x;
  if (idx >= GG * LL) return;
  int g = idx / LL;
  int l = idx - g * LL;
  float c = cnt[g];
  float inv = 1.0f / fmaxf(c, 1.0f);
  float acc = blin[l];
#pragma unroll
  for (int j = 0; j < HH; j++) {
    float mx = __int_as_float(maxp[g * HH + j]);
    float mean = sump[g * HH + j] * inv;
    acc += mx * Wlin[j * LL + l];
    acc += mean * Wlin[(HH + j) * LL + l];
  }
  out[idx] = acc;
}

extern "C" void kernel_launch(void* const* d_in, const int* in_sizes, int n_in,
                              void* d_out, int out_size, void* d_ws,
                              size_t ws_size, hipStream_t stream) {
  const float* x = (const float*)d_in[0];
  const int* edge_index = (const int*)d_in[1];
  const int* batch = (const int*)d_in[2];
  const float* W_rel1 = (const float*)d_in[3];
  const float* b1 = (const float*)d_in[4];
  const float* W_root1 = (const float*)d_in[5];
  const float* W_rel2 = (const float*)d_in[6];
  const float* b2 = (const float*)d_in[7];
  const float* W_root2 = (const float*)d_in[8];
  const float* W_rel3 = (const float*)d_in[9];
  const float* b3 = (const float*)d_in[10];
  const float* W_root3 = (const float*)d_in[11];
  const float* W_lin = (const float*)d_in[12];
  const float* b_lin = (const float*)d_in[13];
  float* out = (float*)d_out;

  const int E = in_sizes[1] / 2;
  const int n_nodes = in_sizes[0] / FF;  // == NN
  const int* src = edge_index;
  const int* dst = edge_index + E;

  // Workspace layout (16B-aligned chunks)
  unsigned int* pay = (unsigned int*)d_ws;       // NB*CAP u32 (14.3MB)
  int* srt = (int*)(pay + (size_t)NB * CAP);     // NB*CAP (14.3MB)
  int* rofs = srt + (size_t)NB * CAP;            // NN
  int* rend = rofs + NN;                         // NN
  int* cursor = rend + NN;                       // 512
  float* sump = (float*)(cursor + 512);          // GG*HH
  int* maxp = (int*)(sump + GG * HH);            // GG*HH
  float* cnt = (float*)(maxp + GG * HH);         // 512
  unsigned short* xb = (unsigned short*)(cnt + 512);  // NN*16 bf16 (3.2MB)
  unsigned short* h1 = xb + (size_t)NN * XPAD;   // NN*24 bf16 (4.8MB)
  unsigned short* h2 = h1 + (size_t)NN * HPAD;   // NN*24 bf16 (4.8MB)

  const int edge_tiles = (E + TILE - 1) / TILE;

  // ---- Cast x to padded bf16 + zero cursors/pool accumulators ----
  cast_init_kernel<<<(n_nodes * XPAD + 255) / 256, 256, 0, stream>>>(
      x, xb, sump, maxp, cnt, cursor, n_nodes * XPAD);

  // ---- Edge partition + one-time CSR build ----
  multisplit_kernel<<<edge_tiles, 512, 0, stream>>>(src, dst, cursor, pay, E);
  bucket_csr_kernel<<<NB, 256, 0, stream>>>(pay, cursor, srt, rofs, rend);

  // ---- Fused per-half-bucket layers (balanced gather, padded rows) ----
  layer_kernel<FF, XPAD, HPAD><<<NB * 2, 512, 0, stream>>>(
      xb, srt, rofs, rend, W_rel1, b1, W_root1, h1);
  layer_kernel<HH, HPAD, HPAD><<<NB * 2, 512, 0, stream>>>(
      h1, srt, rofs, rend, W_rel2, b2, W_root2, h2);
  layer_pool_kernel<<<NB * 2, 512, 0, stream>>>(
      h2, srt, rofs, rend, W_rel3, b3, W_root3, batch, sump, maxp, cnt);

  // ---- Readout ----
  readout_kernel<<<(GG * LL + 255) / 256, 256, 0, stream>>>(
      sump, maxp, cnt, W_lin, b_lin, out);
}

// Round 3
// 277.631 us; speedup vs baseline: 1.1290x; 1.1290x over previous
//
#include <hip/hip_runtime.h>
#include <hip/hip_bf16.h>

#define NN 100000   // nodes
#define FF 10       // input features
#define HH 20       // hidden dim
#define GG 512      // graphs
#define LL 2        // labels

#define NB 500      // dst buckets
#define BNODES 200  // nodes per bucket (NN / NB)
#define CAP 7168    // per-bucket capacity (mean 6400, ~9.6 sigma)
#define HB 100      // nodes per half-bucket (one layer block)
#define SCAP 3712   // per-half-bucket edge capacity (mean 3200, ~9 sigma)
#define TILE 4096   // edges per block in multisplit
#define SRC_BITS 17
#define SRC_MASK 0x1FFFFu

// bf16 helpers (storage-only; all math in f32)
__device__ inline unsigned short f2bf(float f) {
  unsigned u = __float_as_uint(f);
  unsigned r = u + 0x7FFFu + ((u >> 16) & 1u);
  return (unsigned short)(r >> 16);
}
__device__ inline float bflo(unsigned u) { return __uint_as_float(u << 16); }
__device__ inline float bfhi(unsigned u) { return __uint_as_float(u & 0xFFFF0000u); }

// ---------------------------------------------------------------------------
// Cast x f32->bf16 (unpadded, 1:1) and zero cursors/pool accums.
// ---------------------------------------------------------------------------
__global__ __launch_bounds__(256) void cast_init_kernel(
    const float* __restrict__ x, unsigned short* __restrict__ xb,
    float* __restrict__ sump, int* __restrict__ maxp, float* __restrict__ cnt,
    int* __restrict__ cursor, int n) {
  int i = blockIdx.x * 256 + threadIdx.x;
  if (i < n) xb[i] = f2bf(__builtin_nontemporal_load(x + i));
  if (i < GG * HH) {
    sump[i] = 0.0f;
    maxp[i] = 0;
  }
  if (i < GG) cnt[i] = 0.0f;
  if (i < NB) cursor[i] = 0;
}

// ---------------------------------------------------------------------------
// Multisplit (512 thr) with LDS-staged COALESCED writes into fixed-CAP bucket
// regions. Payload pack: (local_dst << 17) | src.   (unchanged)
// ---------------------------------------------------------------------------
__global__ __launch_bounds__(512) void multisplit_kernel(
    const int* __restrict__ src, const int* __restrict__ dst,
    int* __restrict__ cursor, unsigned int* __restrict__ pay, int E) {
  __shared__ int lhist[NB];
  __shared__ int lofs[NB];
  __shared__ int gbase[NB];
  __shared__ int lcur[NB];
  __shared__ unsigned int sord[TILE];
  __shared__ unsigned short sdbk[TILE];
  __shared__ int ss[512];
  int t = threadIdx.x;
  if (t < NB) lhist[t] = 0;
  __syncthreads();

  int base = blockIdx.x * TILE;
  int count = E - base;
  if (count > TILE) count = TILE;

  for (int i = t; i < count; i += 512)
    atomicAdd(&lhist[dst[base + i] / BNODES], 1);
  __syncthreads();

  int own = (t < NB) ? lhist[t] : 0;
  ss[t] = own;
  __syncthreads();
  for (int off = 1; off < 512; off <<= 1) {
    int a0 = (t >= off) ? ss[t - off] : 0;
    __syncthreads();
    ss[t] += a0;
    __syncthreads();
  }
  if (t < NB) {
    lofs[t] = ss[t] - own;
    int bo = own ? atomicAdd(&cursor[t], own) : 0;
    if (bo > CAP - own) bo = CAP - own;
    gbase[t] = t * CAP + bo;
    lcur[t] = 0;
  }
  __syncthreads();

  for (int i = t; i < count; i += 512) {
    int e = base + i;
    int d = __builtin_nontemporal_load(dst + e);
    int s = __builtin_nontemporal_load(src + e);
    int bk = d / BNODES;
    int ld = d - bk * BNODES;
    int r = atomicAdd(&lcur[bk], 1);
    int slot = lofs[bk] + r;
    sord[slot] = ((unsigned)ld << SRC_BITS) | (unsigned)s;
    sdbk[slot] = (unsigned short)bk;
  }
  __syncthreads();

  for (int i = t; i < count; i += 512) {
    int bk = sdbk[i];
    pay[gbase[bk] + (i - lofs[bk])] = sord[i];
  }
}

// ---------------------------------------------------------------------------
// One-time CSR finalize (unchanged): segment per node is contiguous, and
// rend[ln] == rofs[ln+1] within a bucket (dense segments).
// ---------------------------------------------------------------------------
__global__ __launch_bounds__(256) void bucket_csr_kernel(
    const unsigned int* __restrict__ pay, const int* __restrict__ cursor,
    int* __restrict__ srt, int* __restrict__ rofs, int* __restrict__ rend) {
  __shared__ int lhist[BNODES];
  __shared__ int lofs[BNODES];
  __shared__ int lcur[BNODES];
  __shared__ int ss[256];
  int b = blockIdx.x;
  int t = threadIdx.x;
  int k0 = b * CAP;
  int ecnt = cursor[b];
  if (ecnt > CAP) ecnt = CAP;

  if (t < BNODES) lhist[t] = 0;
  __syncthreads();
  for (int k = t; k < ecnt; k += 256)
    atomicAdd(&lhist[pay[k0 + k] >> SRC_BITS], 1);
  __syncthreads();

  int own = (t < BNODES) ? lhist[t] : 0;
  ss[t] = own;
  __syncthreads();
  for (int off = 1; off < 256; off <<= 1) {
    int a0 = (t >= off) ? ss[t - off] : 0;
    __syncthreads();
    ss[t] += a0;
    __syncthreads();
  }
  if (t < BNODES) {
    int ex = ss[t] - own;
    lofs[t] = ex;
    lcur[t] = 0;
    rofs[b * BNODES + t] = k0 + ex;
    rend[b * BNODES + t] = k0 + ex + own;
  }
  __syncthreads();

  for (int k = t; k < ecnt; k += 256) {
    unsigned p = pay[k0 + k];
    int ld = p >> SRC_BITS;
    int r = atomicAdd(&lcur[ld], 1);
    srt[k0 + lofs[ld] + r] = (int)(p & SRC_MASK);
  }
}

// ---------------------------------------------------------------------------
// Fused HALF-bucket layer, v4: UNPADDED rows (min HBM footprint) + balanced
// gather.
//  - gather: 512 threads = NG groups of CL=5 lanes; each group takes an equal
//    contiguous slice of the sorted edge segment; per-lane load is LB bytes
//    (u32 for x rows of 20B, uint2 for h rows of 40B, both naturally
//    aligned); register accumulate; atomicAdd flush into LDS acc at node
//    boundaries (binary search on sRofs; segments are dense).
//  - dense: 4 outputs per thread (HB*5 threads), output stride HH (unpadded).
// ---------------------------------------------------------------------------
template<int DL, int LB>
__global__ __launch_bounds__(512) void layer_kernel(
    const unsigned short* __restrict__ hin, const int* __restrict__ srt,
    const int* __restrict__ rofs, const int* __restrict__ rend,
    const float* __restrict__ Wrel, const float* __restrict__ bias,
    const float* __restrict__ Wroot, unsigned short* __restrict__ hout) {
  constexpr int EL = LB / 2;        // elems per lane
  constexpr int CL = DL / EL;       // lanes per group (5 for both layers)
  constexpr int NG = 512 / CL;      // groups per block
  constexpr int AST = DL + 1;       // acc stride (odd -> bank spread)
  __shared__ int sSrc[SCAP];
  __shared__ float acc[HB * AST];
  __shared__ float rootsf[HB * DL];
  __shared__ __align__(16) float sWrel[DL * HH];
  __shared__ __align__(16) float sWroot[DL * HH];
  __shared__ float sb[HH];
  __shared__ int sRofs[HB];
  __shared__ int sRend[HB];
  __shared__ int sSeg0, sSegLen;
  int b2 = blockIdx.x;
  int t = threadIdx.x;
  int nbase = b2 * HB;

  for (int i = t; i < DL * HH; i += 512) {
    sWrel[i] = Wrel[i];
    sWroot[i] = Wroot[i];
  }
  if (t < HH) sb[t] = bias[t];
  if (t < HB) {
    sRofs[t] = rofs[nbase + t];
    sRend[t] = rend[nbase + t];
  }
  if (t == 0) {
    int s0 = rofs[nbase];
    int sl = rend[nbase + HB - 1] - s0;
    sSeg0 = s0;
    sSegLen = sl < SCAP ? sl : SCAP;
  }
  // roots -> f32 LDS (rows are 4B-aligned: DL even)
  for (int i = t; i < HB * (DL / 2); i += 512) {
    int ln = i / (DL / 2);
    int p = i - ln * (DL / 2);
    unsigned u = *(const unsigned*)(hin + (size_t)(nbase + ln) * DL + 2 * p);
    rootsf[ln * DL + 2 * p] = bflo(u);
    rootsf[ln * DL + 2 * p + 1] = bfhi(u);
  }
  for (int i = t; i < HB * AST; i += 512) acc[i] = 0.0f;
  __syncthreads();

  int seg0 = sSeg0, seglen = sSegLen;
  for (int i = t; i < seglen; i += 512)
    sSrc[i] = __builtin_nontemporal_load(srt + seg0 + i);
  __syncthreads();

  // ---- balanced gather ----
  int g = t / CL;
  int c = t - g * CL;
  if (g < NG) {
    int W = (seglen + NG - 1) / NG;
    int a = g * W;
    if (a > seglen) a = seglen;
    int b = a + W;
    if (b > seglen) b = seglen;
    if (a < b) {
      // binary search: largest ln with sRofs[ln]-seg0 <= a
      int lo = 0, hi = HB - 1;
      while (lo < hi) {
        int mid = (lo + hi + 1) >> 1;
        if (sRofs[mid] - seg0 <= a) lo = mid; else hi = mid - 1;
      }
      int ln = lo;
      const unsigned short* basep = hin + c * EL;
      float a0 = 0, a1 = 0, a2 = 0, a3 = 0;
      int k = a;
      while (k < b) {
        int lim = sRend[ln] - seg0;
        if (lim > b) lim = b;
        if (LB == 8) {
#pragma clang loop unroll_count(8)
          for (; k < lim; ++k) {
            int s = sSrc[k];
            uint2 u = *(const uint2*)(basep + (size_t)s * DL);
            a0 += bflo(u.x); a1 += bfhi(u.x);
            a2 += bflo(u.y); a3 += bfhi(u.y);
          }
        } else {
#pragma clang loop unroll_count(8)
          for (; k < lim; ++k) {
            int s = sSrc[k];
            unsigned u = *(const unsigned*)(basep + (size_t)s * DL);
            a0 += bflo(u); a1 += bfhi(u);
          }
        }
        float* ap = acc + ln * AST + c * EL;
        atomicAdd(ap + 0, a0); atomicAdd(ap + 1, a1);
        if (LB == 8) {
          atomicAdd(ap + 2, a2); atomicAdd(ap + 3, a3);
        }
        a0 = a1 = a2 = a3 = 0.0f;
        ln++;
      }
    }
  }
  __syncthreads();

  // ---- dense: 4 outputs / thread, output stride HH (unpadded) ----
  if (t < HB * 5) {
    int ln = t / 5;
    int jg = t - ln * 5;
    int j0 = jg * 4;
    float v0 = sb[j0], v1 = sb[j0 + 1], v2 = sb[j0 + 2], v3 = sb[j0 + 3];
    const float* ap = acc + ln * AST;
    const float* rp = rootsf + ln * DL;
#pragma unroll
    for (int f = 0; f < DL; ++f) {
      float af = ap[f], rf = rp[f];
      float4 wr = *(const float4*)(sWrel + f * HH + j0);
      float4 wo = *(const float4*)(sWroot + f * HH + j0);
      v0 += af * wr.x + rf * wo.x;
      v1 += af * wr.y + rf * wo.y;
      v2 += af * wr.z + rf * wo.z;
      v3 += af * wr.w + rf * wo.w;
    }
    unsigned short* orow = hout + (size_t)(nbase + ln) * HH;
    uint2 o;
    o.x = ((unsigned)f2bf(fmaxf(v1, 0.0f)) << 16) | f2bf(fmaxf(v0, 0.0f));
    o.y = ((unsigned)f2bf(fmaxf(v3, 0.0f)) << 16) | f2bf(fmaxf(v2, 0.0f));
    *(uint2*)(orow + j0) = o;
  }
}

// ---------------------------------------------------------------------------
// Layer 3 + pooling: same balanced gather + register dense, then block-local
// pool scan + few global atomics (post-ReLU >=0 -> int atomicMax is ordered).
// ---------------------------------------------------------------------------
__global__ __launch_bounds__(512) void layer_pool_kernel(
    const unsigned short* __restrict__ hin, const int* __restrict__ srt,
    const int* __restrict__ rofs, const int* __restrict__ rend,
    const float* __restrict__ Wrel, const float* __restrict__ bias,
    const float* __restrict__ Wroot, const int* __restrict__ batch,
    float* __restrict__ sump, int* __restrict__ maxp,
    float* __restrict__ cnt) {
  constexpr int DL = 20, CL = 5, NG = 102, AST = 21;
  __shared__ int sSrc[SCAP];
  __shared__ float acc[HB * AST];
  __shared__ float rootsf[HB * DL];
  __shared__ __align__(16) float sWrel[DL * HH];
  __shared__ __align__(16) float sWroot[DL * HH];
  __shared__ float sb[HH];
  __shared__ int sRofs[HB];
  __shared__ int sRend[HB];
  __shared__ int sBatch[HB];
  __shared__ int sSeg0, sSegLen;
  int b2 = blockIdx.x;
  int t = threadIdx.x;
  int nbase = b2 * HB;

  for (int i = t; i < DL * HH; i += 512) {
    sWrel[i] = Wrel[i];
    sWroot[i] = Wroot[i];
  }
  if (t < HH) sb[t] = bias[t];
  if (t < HB) {
    sRofs[t] = rofs[nbase + t];
    sRend[t] = rend[nbase + t];
    sBatch[t] = batch[nbase + t];
  }
  if (t == 0) {
    int s0 = rofs[nbase];
    int sl = rend[nbase + HB - 1] - s0;
    sSeg0 = s0;
    sSegLen = sl < SCAP ? sl : SCAP;
  }
  for (int i = t; i < HB * (DL / 2); i += 512) {
    int ln = i / (DL / 2);
    int p = i - ln * (DL / 2);
    unsigned u = *(const unsigned*)(hin + (size_t)(nbase + ln) * DL + 2 * p);
    rootsf[ln * DL + 2 * p] = bflo(u);
    rootsf[ln * DL + 2 * p + 1] = bfhi(u);
  }
  for (int i = t; i < HB * AST; i += 512) acc[i] = 0.0f;
  __syncthreads();

  int seg0 = sSeg0, seglen = sSegLen;
  for (int i = t; i < seglen; i += 512)
    sSrc[i] = __builtin_nontemporal_load(srt + seg0 + i);
  __syncthreads();

  // ---- balanced gather (uint2 lanes over 40B rows) ----
  int g = t / CL;
  int c = t - g * CL;
  if (g < NG) {
    int W = (seglen + NG - 1) / NG;
    int a = g * W;
    if (a > seglen) a = seglen;
    int b = a + W;
    if (b > seglen) b = seglen;
    if (a < b) {
      int lo = 0, hi = HB - 1;
      while (lo < hi) {
        int mid = (lo + hi + 1) >> 1;
        if (sRofs[mid] - seg0 <= a) lo = mid; else hi = mid - 1;
      }
      int ln = lo;
      const unsigned short* basep = hin + c * 4;
      float a0 = 0, a1 = 0, a2 = 0, a3 = 0;
      int k = a;
      while (k < b) {
        int lim = sRend[ln] - seg0;
        if (lim > b) lim = b;
#pragma clang loop unroll_count(8)
        for (; k < lim; ++k) {
          int s = sSrc[k];
          uint2 u = *(const uint2*)(basep + (size_t)s * DL);
          a0 += bflo(u.x); a1 += bfhi(u.x);
          a2 += bflo(u.y); a3 += bfhi(u.y);
        }
        float* ap = acc + ln * AST + c * 4;
        atomicAdd(ap + 0, a0); atomicAdd(ap + 1, a1);
        atomicAdd(ap + 2, a2); atomicAdd(ap + 3, a3);
        a0 = a1 = a2 = a3 = 0.0f;
        ln++;
      }
    }
  }
  __syncthreads();

  // ---- dense into registers (acc still needed as input) ----
  float v0 = 0, v1 = 0, v2 = 0, v3 = 0;
  int ln0 = 0, j0 = 0;
  if (t < HB * 5) {
    ln0 = t / 5;
    int jg = t - ln0 * 5;
    j0 = jg * 4;
    v0 = sb[j0]; v1 = sb[j0 + 1]; v2 = sb[j0 + 2]; v3 = sb[j0 + 3];
    const float* ap = acc + ln0 * AST;
    const float* rp = rootsf + ln0 * DL;
#pragma unroll
    for (int f = 0; f < DL; ++f) {
      float af = ap[f], rf = rp[f];
      float4 wr = *(const float4*)(sWrel + f * HH + j0);
      float4 wo = *(const float4*)(sWroot + f * HH + j0);
      v0 += af * wr.x + rf * wo.x;
      v1 += af * wr.y + rf * wo.y;
      v2 += af * wr.z + rf * wo.z;
      v3 += af * wr.w + rf * wo.w;
    }
    v0 = fmaxf(v0, 0.0f); v1 = fmaxf(v1, 0.0f);
    v2 = fmaxf(v2, 0.0f); v3 = fmaxf(v3, 0.0f);
  }
  __syncthreads();
  if (t < HB * 5) {
    float* ap = acc + ln0 * AST + j0;
    ap[0] = v0; ap[1] = v1; ap[2] = v2; ap[3] = v3;
  }
  __syncthreads();

  // ---- block-local pool + global atomics ----
  int g0 = sBatch[0];
  int g1 = sBatch[HB - 1];
  int ngr = g1 - g0 + 1;
  for (int it = t; it < ngr * HH; it += 512) {
    int gi = it / HH;
    int j = it - gi * HH;
    int gph = g0 + gi;
    float s = 0.0f, m = 0.0f;
    int c2 = 0;
    for (int ln = 0; ln < HB; ln++) {
      if (sBatch[ln] == gph) {
        float v = acc[ln * AST + j];
        s += v;
        m = fmaxf(m, v);
        c2++;
      }
    }
    if (c2) {
      atomicAdd(&sump[gph * HH + j], s);
      atomicMax(&maxp[gph * HH + j], __float_as_int(m));
      if (j == 0) atomicAdd(&cnt[gph], (float)c2);
    }
  }
}

__global__ __launch_bounds__(256) void readout_kernel(
    const float* __restrict__ sump, const int* __restrict__ maxp,
    const float* __restrict__ cnt, const float* __restrict__ Wlin,
    const float* __restrict__ blin, float* __restrict__ out) {
  int idx = blockIdx.x * 256 + threadIdx.x;
  if (idx >= GG * LL) return;
  int g = idx / LL;
  int l = idx - g * LL;
  float c = cnt[g];
  float inv = 1.0f / fmaxf(c, 1.0f);
  float acc = blin[l];
#pragma unroll
  for (int j = 0; j < HH; j++) {
    float mx = __int_as_float(maxp[g * HH + j]);
    float mean = sump[g * HH + j] * inv;
    acc += mx * Wlin[j * LL + l];
    acc += mean * Wlin[(HH + j) * LL + l];
  }
  out[idx] = acc;
}

extern "C" void kernel_launch(void* const* d_in, const int* in_sizes, int n_in,
                              void* d_out, int out_size, void* d_ws,
                              size_t ws_size, hipStream_t stream) {
  const float* x = (const float*)d_in[0];
  const int* edge_index = (const int*)d_in[1];
  const int* batch = (const int*)d_in[2];
  const float* W_rel1 = (const float*)d_in[3];
  const float* b1 = (const float*)d_in[4];
  const float* W_root1 = (const float*)d_in[5];
  const float* W_rel2 = (const float*)d_in[6];
  const float* b2 = (const float*)d_in[7];
  const float* W_root2 = (const float*)d_in[8];
  const float* W_rel3 = (const float*)d_in[9];
  const float* b3 = (const float*)d_in[10];
  const float* W_root3 = (const float*)d_in[11];
  const float* W_lin = (const float*)d_in[12];
  const float* b_lin = (const float*)d_in[13];
  float* out = (float*)d_out;

  const int E = in_sizes[1] / 2;
  const int n_nodes = in_sizes[0] / FF;  // == NN
  const int* src = edge_index;
  const int* dst = edge_index + E;

  // Workspace layout (16B-aligned chunks)
  unsigned int* pay = (unsigned int*)d_ws;       // NB*CAP u32 (14.3MB)
  int* srt = (int*)(pay + (size_t)NB * CAP);     // NB*CAP (14.3MB)
  int* rofs = srt + (size_t)NB * CAP;            // NN
  int* rend = rofs + NN;                         // NN
  int* cursor = rend + NN;                       // 512
  float* sump = (float*)(cursor + 512);          // GG*HH
  int* maxp = (int*)(sump + GG * HH);            // GG*HH
  float* cnt = (float*)(maxp + GG * HH);         // 512
  unsigned short* xb = (unsigned short*)(cnt + 512);  // NN*FF bf16 (2MB)
  unsigned short* h1 = xb + (size_t)NN * FF;     // NN*HH bf16 (4MB)
  unsigned short* h2 = h1 + (size_t)NN * HH;     // NN*HH bf16 (4MB)

  const int edge_tiles = (E + TILE - 1) / TILE;

  // ---- Cast x to bf16 + zero cursors/pool accumulators ----
  cast_init_kernel<<<(n_nodes * FF + 255) / 256, 256, 0, stream>>>(
      x, xb, sump, maxp, cnt, cursor, n_nodes * FF);

  // ---- Edge partition + one-time CSR build ----
  multisplit_kernel<<<edge_tiles, 512, 0, stream>>>(src, dst, cursor, pay, E);
  bucket_csr_kernel<<<NB, 256, 0, stream>>>(pay, cursor, srt, rofs, rend);

  // ---- Fused per-half-bucket layers (balanced gather, unpadded rows) ----
  layer_kernel<FF, 4><<<NB * 2, 512, 0, stream>>>(
      xb, srt, rofs, rend, W_rel1, b1, W_root1, h1);
  layer_kernel<HH, 8><<<NB * 2, 512, 0, stream>>>(
      h1, srt, rofs, rend, W_rel2, b2, W_root2, h2);
  layer_pool_kernel<<<NB * 2, 512, 0, stream>>>(
      h2, srt, rofs, rend, W_rel3, b3, W_root3, batch, sump, maxp, cnt);

  // ---- Readout ----
  readout_kernel<<<(GG * LL + 255) / 256, 256, 0, stream>>>(
      sump, maxp, cnt, W_lin, b_lin, out);
}